// Round 4
// baseline (327.553 us; speedup 1.0000x reference)
//
#include <hip/hip_runtime.h>

typedef float f32x2 __attribute__((ext_vector_type(2)));
typedef float f32x4 __attribute__((ext_vector_type(4)));

// Problem constants (from reference)
constexpr int S  = 4096;   // N_SAMPLES
constexpr int W  = 16;     // N_WIDTH
constexpr int NN = 193;    // N_NODES
constexpr int DD = 2;      // NDIM_IN
constexpr int SW = S * W;                      // 65536
constexpr int PHI_OFF = 3 * SW;                // after t, dt, ddt
constexpr int PHI_SZ  = SW * NN * DD;          // 25,296,896 per tensor
constexpr long DX_OFF = (long)PHI_OFF + 3L * PHI_SZ;  // 76,087,296

constexpr int ROW_F = NN * DD;   // 386 dwords per (i,k) row = 193 f2
constexpr int ROW_P = 388;       // padded so 3*ROW_P is f4-divisible for zeroing

__global__ __launch_bounds__(256)
void kan_fused_kernel(const float* __restrict__ x,
                      const float* __restrict__ w,
                      float* __restrict__ out) {
    const int i   = blockIdx.x;
    const int tid = threadIdx.x;

    __shared__ __align__(16) float row[3][ROW_P];   // 4656 B
    __shared__ float vals[3][DD][4];
    __shared__ int   nls[DD];

    // Phase 1a: zero the rows (3*388 = 1164 dwords = 291 f4, exact)
    {
        f32x4* rz = (f32x4*)(&row[0][0]);
        for (int idx = tid; idx < 3 * ROW_P / 4; idx += 256)
            rz[idx] = (f32x4){0.f, 0.f, 0.f, 0.f};
    }

    // Phase 1b: threads 0,1 compute the Lagrange basis for dim d = tid
    if (tid < DD) {
        const int d = tid;
        float xv = x[i * DD + d];
        float xs = 192.0f * xv;                  // (N_NODES-1)*(x-xmin)/(xmax-xmin)
        float fe = floorf(xs / 3.0f);            // element index
        fe = fminf(fmaxf(fe, 0.0f), 63.0f);      // clip to [0, N_ELEMENTS-1]
        int nl = (int)(fe * 3.0f);               // left node index
        nls[d] = nl;
        float xr = 2.0f * (xs - (float)nl) / 3.0f - 1.0f;   // ref coord in [-1,1]

        // Cubic Lagrange basis at nodes {-1,-1/3,1/3,1}
        float xp1 = xr + 1.0f;
        float xm1 = xr - 1.0f;
        float x2  = xr * xr;
        float x2m = x2 - (1.0f / 9.0f);          // (x+1/3)(x-1/3)
        const float c0 = 0.5625f;                // 9/16
        const float c1 = 1.6875f;                // 27/16

        vals[0][d][0] = -c0 * x2m * xm1;
        vals[0][d][1] =  c1 * xp1 * (xr - (1.0f / 3.0f)) * xm1;
        vals[0][d][2] = -c1 * xp1 * (xr + (1.0f / 3.0f)) * xm1;
        vals[0][d][3] =  c0 * xp1 * x2m;

        const float idx1 = 128.0f;               // 1/delta_x (exact, 2^7)
        vals[1][d][0] = -c0 * (3.0f * x2 - 2.0f * xr - (1.0f / 9.0f)) * idx1;
        vals[1][d][1] =  c1 * (3.0f * x2 - (2.0f / 3.0f) * xr - 1.0f) * idx1;
        vals[1][d][2] = -c1 * (3.0f * x2 + (2.0f / 3.0f) * xr - 1.0f) * idx1;
        vals[1][d][3] =  c0 * (3.0f * x2 + 2.0f * xr - (1.0f / 9.0f)) * idx1;

        const float idx2 = 16384.0f;             // 1/delta_x^2 (exact, 2^14)
        vals[2][d][0] = -c0 * (6.0f * xr - 2.0f) * idx2;
        vals[2][d][1] =  c1 * (6.0f * xr - (2.0f / 3.0f)) * idx2;
        vals[2][d][2] = -c1 * (6.0f * xr + (2.0f / 3.0f)) * idx2;
        vals[2][d][3] =  c0 * (6.0f * xr + 2.0f) * idx2;
    }

    __syncthreads();

    // Phase 2a: scatter the 24 nonzero entries into the LDS rows
    if (tid < 24) {
        int a = tid >> 3;           // tensor 0..2
        int r = tid & 7;
        int d = r >> 2;             // dim 0..1
        int p = r & 3;              // local basis index 0..3
        row[a][(nls[d] + p) * DD + d] = vals[a][d][p];
    }

    // Phase 2b: t/dt/ddt dot products (only needs vals/nls)
    if (tid < 48) {
        int k = tid / 3;            // width 0..15
        int a = tid % 3;            // tensor 0..2
        float s = 0.0f;
#pragma unroll
        for (int d = 0; d < DD; ++d) {
            int base = k * (NN * DD) + nls[d] * DD + d;
#pragma unroll
            for (int p = 0; p < 4; ++p)
                s += w[base + p * DD] * vals[a][d][p];
        }
        out[a * SW + i * W + k] = s;
    }

    if (i == 0 && tid == 0)
        out[DX_OFF] = 0.0078125f;   // delta_x

    __syncthreads();

    // Phase 3: each thread reads its f2 slot of the row ONCE, then stores the
    // 16 k-copies with fully-coalesced f2 stores at compile-time offsets.
    // Threads 192..207 handle the last f2 slot's 16 copies in one instruction.
#pragma unroll
    for (int a = 0; a < 3; ++a) {
        f32x2* dst = (f32x2*)(out + PHI_OFF + (size_t)a * PHI_SZ)
                     + (size_t)i * (W * NN);
        if (tid < 192) {
            f32x2 v = *(const f32x2*)(&row[a][2 * tid]);
            f32x2* p = dst + tid;
#pragma unroll
            for (int j = 0; j < 16; ++j)
                p[j * NN] = v;
        } else if (tid < 208) {
            int j = tid - 192;
            f32x2 v = *(const f32x2*)(&row[a][2 * 192]);
            dst[j * NN + 192] = v;
        }
    }
}

extern "C" void kernel_launch(void* const* d_in, const int* in_sizes, int n_in,
                              void* d_out, int out_size, void* d_ws, size_t ws_size,
                              hipStream_t stream) {
    const float* x = (const float*)d_in[0];   // (4096, 2) fp32
    const float* w = (const float*)d_in[1];   // (16, 193, 2) fp32
    float* out = (float*)d_out;

    kan_fused_kernel<<<S, 256, 0, stream>>>(x, w, out);
}

// Round 5
// 303.137 us; speedup vs baseline: 1.0805x; 1.0805x over previous
//
#include <hip/hip_runtime.h>

typedef float f32x4 __attribute__((ext_vector_type(4)));

// Problem constants (from reference)
constexpr int S  = 4096;   // N_SAMPLES
constexpr int W  = 16;     // N_WIDTH
constexpr int NN = 193;    // N_NODES
constexpr int DD = 2;      // NDIM_IN
constexpr int SW = S * W;                      // 65536
constexpr int PHI_OFF = 3 * SW;                // after t, dt, ddt
constexpr int PHI_SZ  = SW * NN * DD;          // 25,296,896 floats per tensor
constexpr long DX_OFF = (long)PHI_OFF + 3L * PHI_SZ;  // 76,087,296

constexpr int ROW_F    = NN * DD;      // 386 floats per (i,k) row
constexpr int CHUNK_F4 = W * ROW_F / 4; // 1544 f4 per (a,i) chunk

// Lagrange basis (cubic, nodes {-1,-1/3,1/3,1}) for one dim; returns the 4
// values of tensor `a` (0=phi, 1=dphi/dx, 2=ddphi/dx^2) plus left node index.
__device__ __forceinline__ void basis(int a, float xvd, int& nl,
                                      float& c0, float& c1, float& c2, float& c3) {
    float xs = 192.0f * xvd;
    float fe = floorf(xs * (1.0f / 3.0f));
    fe = fminf(fmaxf(fe, 0.0f), 63.0f);
    nl = (int)(fe * 3.0f);
    float xr = 2.0f * (xs - (float)nl) * (1.0f / 3.0f) - 1.0f;

    const float k0 = 0.5625f;    // 9/16
    const float k1 = 1.6875f;    // 27/16
    float xp1 = xr + 1.0f;
    float xm1 = xr - 1.0f;
    float x2  = xr * xr;
    float x2m = x2 - (1.0f / 9.0f);

    if (a == 0) {
        c0 = -k0 * x2m * xm1;
        c1 =  k1 * xp1 * (xr - (1.0f / 3.0f)) * xm1;
        c2 = -k1 * xp1 * (xr + (1.0f / 3.0f)) * xm1;
        c3 =  k0 * xp1 * x2m;
    } else if (a == 1) {
        const float s1 = 128.0f;  // 1/delta_x (exact 2^7)
        c0 = -k0 * (3.0f * x2 - 2.0f * xr - (1.0f / 9.0f)) * s1;
        c1 =  k1 * (3.0f * x2 - (2.0f / 3.0f) * xr - 1.0f) * s1;
        c2 = -k1 * (3.0f * x2 + (2.0f / 3.0f) * xr - 1.0f) * s1;
        c3 =  k0 * (3.0f * x2 + 2.0f * xr - (1.0f / 9.0f)) * s1;
    } else {
        const float s2 = 16384.0f; // 1/delta_x^2 (exact 2^14)
        c0 = -k0 * (6.0f * xr - 2.0f) * s2;
        c1 =  k1 * (6.0f * xr - (2.0f / 3.0f)) * s2;
        c2 = -k1 * (6.0f * xr + (2.0f / 3.0f)) * s2;
        c3 =  k0 * (6.0f * xr + 2.0f) * s2;
    }
}

__device__ __forceinline__ float pick4(int rel, float c0, float c1, float c2, float c3) {
    float r = 0.0f;
    r = (rel == 0) ? c0 : r;
    r = (rel == 1) ? c1 : r;
    r = (rel == 2) ? c2 : r;
    r = (rel == 3) ? c3 : r;
    return r;
}

// One block per (tensor a, sample i), a = high bits so the resident block set
// covers one dense address window of a single tensor region. No LDS, no
// barriers: every thread holds the 8 basis values in registers.
__global__ __launch_bounds__(256)
void kan_kernel(const float* __restrict__ x,
                const float* __restrict__ w,
                float* __restrict__ out) {
    const int b   = blockIdx.x;
    const int a   = b >> 12;      // tensor 0..2
    const int i   = b & 4095;     // sample
    const int tid = threadIdx.x;

    const float xv0 = x[2 * i];
    const float xv1 = x[2 * i + 1];

    int nl0, nl1;
    float v00, v01, v02, v03, v10, v11, v12, v13;
    basis(a, xv0, nl0, v00, v01, v02, v03);
    basis(a, xv1, nl1, v10, v11, v12, v13);

    // t/dt/ddt row for this (a, i): 16 dot products, 8 terms each.
    if (tid < W) {
        const float* wk = w + tid * ROW_F;
        float s = 0.0f;
        s += wk[(nl0 + 0) * 2 + 0] * v00;
        s += wk[(nl0 + 1) * 2 + 0] * v01;
        s += wk[(nl0 + 2) * 2 + 0] * v02;
        s += wk[(nl0 + 3) * 2 + 0] * v03;
        s += wk[(nl1 + 0) * 2 + 1] * v10;
        s += wk[(nl1 + 1) * 2 + 1] * v11;
        s += wk[(nl1 + 2) * 2 + 1] * v12;
        s += wk[(nl1 + 3) * 2 + 1] * v13;
        out[a * SW + i * W + tid] = s;
    }
    if (b == 0 && tid == 0)
        out[DX_OFF] = 0.0078125f;   // delta_x

    // Dense f4 sweep of this block's 24,704-byte chunk (16 identical rows of
    // 386 floats). Element index e = (4*p) mod 386, maintained incrementally.
    f32x4* dst = (f32x4*)(out + PHI_OFF + (size_t)a * PHI_SZ)
                 + (size_t)i * CHUNK_F4;

    int e = 4 * tid;                 // 0..1020
    if (e >= 772) e -= 772;
    else if (e >= 386) e -= 386;

    for (int p = tid; p < CHUNK_F4; p += 256) {
        f32x4 vv;
#pragma unroll
        for (int j = 0; j < 4; ++j) {
            int ee = e + j;
            if (ee >= ROW_F) ee -= ROW_F;   // rows identical -> wrap is safe
            int n = ee >> 1;
            float p0 = pick4(n - nl0, v00, v01, v02, v03);
            float p1 = pick4(n - nl1, v10, v11, v12, v13);
            vv[j] = (ee & 1) ? p1 : p0;
        }
        dst[p] = vv;
        e += (256 * 4) % ROW_F;          // +252
        if (e >= ROW_F) e -= ROW_F;
    }
}

extern "C" void kernel_launch(void* const* d_in, const int* in_sizes, int n_in,
                              void* d_out, int out_size, void* d_ws, size_t ws_size,
                              hipStream_t stream) {
    const float* x = (const float*)d_in[0];   // (4096, 2) fp32
    const float* w = (const float*)d_in[1];   // (16, 193, 2) fp32
    float* out = (float*)d_out;

    kan_kernel<<<3 * S, 256, 0, stream>>>(x, w, out);
}